// Round 5
// baseline (225.732 us; speedup 1.0000x reference)
//
#include <hip/hip_runtime.h>
#include <hip/hip_bf16.h>

#define BB 2
#define CC 128
#define HH 48
#define WW 48
#define NN (HH*WW)            // 2304
#define PB 26                 // 25 bins + spill (only ever gets +0.0)
#define HST 27                // private hist stride
#define QT 16                 // queries per block
#define MT 64                 // m per iteration (4 waves x 16 rows)
#define MSPLIT 4              // m-range split -> 1152 blocks
#define NTILES (NN/QT)        // 144
#define ITERS (NN/MSPLIT/MT)  // 9
#define SLICE (QT*PB)         // 416 floats per partial slice
#define PSCALE 65536.0f
#define PINV   (1.0f/65536.0f)

typedef __bf16 bf16x8 __attribute__((ext_vector_type(8)));
typedef float  f32x4  __attribute__((ext_vector_type(4)));
typedef unsigned short u16;
typedef unsigned int   u32;

static __device__ __forceinline__ u16 f2bf(float x) {
    __hip_bfloat16 h = __float2bfloat16(x);
    return __builtin_bit_cast(u16, h);
}

// Fused producer: blocks [0,144) transpose img1 -> Qt[b][n][c]; blocks
// [144,288) bilinear grid-sample img2 -> Dt[b][m][c]. Also zeroes d_out and
// the per-group done-counters (one per block index).
__global__ __launch_bounds__(256)
void k_prep(const float* __restrict__ img1, const float* __restrict__ img2,
            const float* __restrict__ grid, u16* __restrict__ Qt,
            u16* __restrict__ Dt, u32* __restrict__ cnt, float* __restrict__ out) {
    int blk = blockIdx.x;
    if (threadIdx.x == 0) cnt[blk] = 0u;           // 288 groups == 288 blocks
    if (blk == 0 && threadIdx.x == 0) out[0] = 0.0f;
    bool isg = blk >= 144;
    int bb  = isg ? blk - 144 : blk;
    int bm  = (bb >> 3) * 256 + threadIdx.x;       // b*NN + n, 18*256 = 4608
    int cc0 = (bb & 7) * 16;
    int b   = bm / NN;
    int p   = bm - b * NN;
    u16 tmp[16];
    if (!isg) {
        const float* im = img1 + (size_t)b * CC * NN + (size_t)cc0 * NN;
        #pragma unroll
        for (int c = 0; c < 16; ++c) tmp[c] = f2bf(im[(size_t)c * NN + p]);
        uint4* dst = reinterpret_cast<uint4*>(Qt + (size_t)bm * CC + cc0);
        dst[0] = *reinterpret_cast<uint4*>(&tmp[0]);
        dst[1] = *reinterpret_cast<uint4*>(&tmp[8]);
    } else {
        float gx = grid[bm * 2 + 0];
        float gy = grid[bm * 2 + 1];
        float ix = ((gx + 1.0f) * (float)WW - 1.0f) * 0.5f;
        float iy = ((gy + 1.0f) * (float)HH - 1.0f) * 0.5f;
        float x0f = floorf(ix), y0f = floorf(iy);
        float wx1 = ix - x0f, wy1 = iy - y0f;
        float wx0 = 1.0f - wx1, wy0 = 1.0f - wy1;
        int x0 = (int)x0f, y0 = (int)y0f;
        bool xv0 = (x0 >= 0) && (x0 < WW);
        bool xv1 = (x0 + 1 >= 0) && (x0 + 1 < WW);
        bool yv0 = (y0 >= 0) && (y0 < HH);
        bool yv1 = (y0 + 1 >= 0) && (y0 + 1 < HH);
        int x0c = min(max(x0, 0), WW - 1), x1c = min(max(x0 + 1, 0), WW - 1);
        int y0c = min(max(y0, 0), HH - 1), y1c = min(max(y0 + 1, 0), HH - 1);
        float w00 = (xv0 && yv0) ? wx0 * wy0 : 0.0f;
        float w01 = (xv1 && yv0) ? wx1 * wy0 : 0.0f;
        float w10 = (xv0 && yv1) ? wx0 * wy1 : 0.0f;
        float w11 = (xv1 && yv1) ? wx1 * wy1 : 0.0f;
        int p00 = y0c * WW + x0c, p01 = y0c * WW + x1c;
        int p10 = y1c * WW + x0c, p11 = y1c * WW + x1c;
        const float* im = img2 + (size_t)b * CC * NN + (size_t)cc0 * NN;
        #pragma unroll
        for (int c = 0; c < 16; ++c) {
            const float* pl = im + (size_t)c * NN;
            tmp[c] = f2bf(pl[p00] * w00 + pl[p01] * w01 + pl[p10] * w10 + pl[p11] * w11);
        }
        uint4* dst = reinterpret_cast<uint4*>(Dt + (size_t)bm * CC + cc0);
        dst[0] = *reinterpret_cast<uint4*>(&tmp[0]);
        dst[1] = *reinterpret_cast<uint4*>(&tmp[8]);
    }
}

// main: 16x16x32 MFMA, C[m][q], q = lane&15. NO LDS tile staging: each D row
// is consumed by exactly one wave -> A-fragments loaded global->VGPR directly
// (prefetched one iter ahead, 64B-coalesced); Q fragments (iter-invariant)
// hoisted to VGPRs. LDS holds only the per-thread private hists (plain RMW)
// and the u32 fixed-point positives hist. Last block of each (b,ntile) group
// combines the MSPLIT slices and folds reliability into the scalar loss.
__global__ __launch_bounds__(256)
void k_main(const u16* __restrict__ Qt, const u16* __restrict__ Dt,
            float* __restrict__ Hall, float* __restrict__ Hpos,
            u32* __restrict__ cnt, const float* __restrict__ rel,
            float* __restrict__ out) {
    __shared__ float priv[256 * HST];   // 27648 B per-thread hists (reused as comb)
    __shared__ u32   poshu[QT * PB];    //  1664 B positives (u32 fixed-point)
    __shared__ int   lastflag;

    int tid  = threadIdx.x;
    int bidx = blockIdx.x;              // ((b*144 + ntile)*4 + ms)
    int b     = bidx / (NTILES * MSPLIT);
    int rem   = bidx % (NTILES * MSPLIT);
    int ntile = rem / MSPLIT;
    int ms    = rem % MSPLIT;
    int n0  = ntile * QT;
    int grp = b * NTILES + ntile;

    for (int i = tid; i < 256 * HST; i += 256) priv[i] = 0.0f;
    for (int i = tid; i < QT * PB; i += 256) poshu[i] = 0u;

    int lane = tid & 63, wave = tid >> 6, quad = lane >> 4, l15 = lane & 15;
    int q  = l15;
    int n  = n0 + q;
    int rn = n / WW, cn = n % WW;
    float* ph = &priv[tid * HST];

    // B fragments (Q rows) — iter-invariant, straight from global
    const u16* qrow = Qt + ((size_t)(b * NN + n0 + l15)) * CC + quad * 8;
    bf16x8 bv0 = *reinterpret_cast<const bf16x8*>(qrow);
    bf16x8 bv1 = *reinterpret_cast<const bf16x8*>(qrow + 32);
    bf16x8 bv2 = *reinterpret_cast<const bf16x8*>(qrow + 64);
    bf16x8 bv3 = *reinterpret_cast<const bf16x8*>(qrow + 96);

    __syncthreads();                    // hist zero-init visible to all

    int mstart = ms * (NN / MSPLIT);
    const u16* arow = Dt + ((size_t)(b * NN + mstart + wave * 16 + l15)) * CC + quad * 8;
    bf16x8 a0 = *reinterpret_cast<const bf16x8*>(arow);
    bf16x8 a1 = *reinterpret_cast<const bf16x8*>(arow + 32);
    bf16x8 a2 = *reinterpret_cast<const bf16x8*>(arow + 64);
    bf16x8 a3 = *reinterpret_cast<const bf16x8*>(arow + 96);

    for (int it = 0; it < ITERS; ++it) {
        bf16x8 c0 = a0, c1 = a1, c2 = a2, c3 = a3;
        if (it + 1 < ITERS) {           // prefetch next iter's A rows
            const u16* nx = arow + (size_t)(it + 1) * MT * CC;
            a0 = *reinterpret_cast<const bf16x8*>(nx);
            a1 = *reinterpret_cast<const bf16x8*>(nx + 32);
            a2 = *reinterpret_cast<const bf16x8*>(nx + 64);
            a3 = *reinterpret_cast<const bf16x8*>(nx + 96);
        }
        f32x4 acc = {0.f, 0.f, 0.f, 0.f};
        acc = __builtin_amdgcn_mfma_f32_16x16x32_bf16(c0, bv0, acc, 0, 0, 0);
        acc = __builtin_amdgcn_mfma_f32_16x16x32_bf16(c1, bv1, acc, 0, 0, 0);
        acc = __builtin_amdgcn_mfma_f32_16x16x32_bf16(c2, bv2, acc, 0, 0, 0);
        acc = __builtin_amdgcn_mfma_f32_16x16x32_bf16(c3, bv3, acc, 0, 0, 0);

        int mb = mstart + it * MT + wave * 16 + quad * 4;  // C row = quad*4+i
        #pragma unroll
        for (int i = 0; i < 4; ++i) {
            float s  = acc[i];
            float t  = fminf(fmaxf(fmaf(-12.0f, s, 12.0f), 0.0f), 24.0f);
            float cf = floorf(t);
            float f  = t - cf;
            int   c0b = (int)cf;        // [0,24]; c0==24 -> f==0 -> spill +0
            float h0 = ph[c0b], h1 = ph[c0b + 1];
            ph[c0b]     = h0 + (1.0f - f);   // private -> plain RMW, race-free
            ph[c0b + 1] = h1 + f;
            int m  = mb + i;
            int rm = m / WW, cm = m - rm * WW;
            int dr = rn - rm, dc = cn - cm;
            if ((unsigned)(dr + 4) <= 8u && (unsigned)(dc + 4) <= 8u) {
                u32 w0 = (u32)(fmaf(-PSCALE, f, PSCALE) + 0.5f);
                u32 w1 = (u32)(f * PSCALE + 0.5f);
                atomicAdd(&poshu[q * PB + c0b],     w0);   // native u32 LDS atomic
                atomicAdd(&poshu[q * PB + c0b + 1], w1);
            }
        }
    }
    __syncthreads();
    // flush partial slices, [c][q] layout (coalesced both sides)
    float* oa = Hall + (size_t)bidx * SLICE;
    float* op = Hpos + (size_t)bidx * SLICE;
    for (int idx = tid; idx < SLICE; idx += 256) {
        int c = idx >> 4, qq = idx & 15;
        float s2 = 0.0f;
        #pragma unroll
        for (int j = 0; j < 16; ++j) s2 += priv[(j * 16 + qq) * HST + c];
        oa[idx] = s2;
        op[idx] = (float)poshu[qq * PB + c] * PINV;
    }
    __threadfence();                    // release this block's slice stores
    __syncthreads();
    if (tid == 0) {
        u32 old = atomicAdd(&cnt[grp], 1u);
        lastflag = (old == MSPLIT - 1);
    }
    __syncthreads();
    if (!lastflag) return;

    // ---- last block of this (b,ntile) group: finalize its 16 queries ----
    __threadfence();                    // acquire other blocks' slices
    float* comb = priv;                 // alias dead private hists: [2][SLICE]
    const float* ga = Hall + (size_t)grp * MSPLIT * SLICE;
    const float* gp = Hpos + (size_t)grp * MSPLIT * SLICE;
    for (int idx = tid; idx < SLICE; idx += 256) {
        float sa = 0.f, sp = 0.f;
        #pragma unroll
        for (int s = 0; s < MSPLIT; ++s) {
            sa += ga[(size_t)s * SLICE + idx];
            sp += gp[(size_t)s * SLICE + idx];
        }
        comb[idx]         = sa;
        comb[SLICE + idx] = sp;
    }
    __syncthreads();
    if (tid < 16) {
        float cumr = 0.f, cumn = 0.f, apn = 0.f, totr = 0.f;
        #pragma unroll
        for (int c = 0; c < 25; ++c) {
            float a = comb[c * 16 + tid];
            float r = comb[SLICE + c * 16 + tid];
            cumr += r; cumn += a;
            apn  += (cumr / (1e-16f + cumn)) * r;
            totr += r;
        }
        float ap = apn / totr;          // totr >= 1 (self-match positive)
        float rl = rel[b * NN + n0 + tid];
        float loss = 1.0f - (ap * rl + 0.5f * (1.0f - rl));
        #pragma unroll
        for (int off = 8; off > 0; off >>= 1) loss += __shfl_down(loss, off, 16);
        if (tid == 0) atomicAdd(out, loss * (1.0f / (float)(BB * NN)));
    }
}

extern "C" void kernel_launch(void* const* d_in, const int* in_sizes, int n_in,
                              void* d_out, int out_size, void* d_ws, size_t ws_size,
                              hipStream_t stream) {
    const float* img1 = (const float*)d_in[0];
    const float* img2 = (const float*)d_in[1];
    const float* rel  = (const float*)d_in[2];
    const float* grid = (const float*)d_in[3];

    char* ws = (char*)d_ws;
    const size_t qt_bytes   = (size_t)BB * NN * CC * sizeof(u16);                    // 1.18 MB
    const size_t part_bytes = (size_t)BB * NTILES * MSPLIT * SLICE * sizeof(float);  // 1.92 MB
    u16*   Qt   = (u16*)ws;
    u16*   Dt   = (u16*)(ws + qt_bytes);
    float* Hall = (float*)(ws + 2 * qt_bytes);
    float* Hpos = (float*)(ws + 2 * qt_bytes + part_bytes);
    u32*   cnt  = (u32*)  (ws + 2 * qt_bytes + 2 * part_bytes);   // 288 u32

    k_prep<<<288, 256, 0, stream>>>(img1, img2, grid, Qt, Dt, cnt, (float*)d_out);
    k_main<<<BB * NTILES * MSPLIT, 256, 0, stream>>>(Qt, Dt, Hall, Hpos, cnt, rel, (float*)d_out);
}

// Round 6
// 99.757 us; speedup vs baseline: 2.2628x; 2.2628x over previous
//
#include <hip/hip_runtime.h>
#include <hip/hip_bf16.h>

#define BB 2
#define CC 128
#define HH 48
#define WW 48
#define NN (HH*WW)            // 2304
#define PB 26                 // 25 bins + spill (only ever gets +0.0)
#define HST 27                // private hist stride
#define QT 16                 // queries per block
#define MT 64                 // m per iteration (4 waves x 16 rows)
#define MSPLIT 4              // m-range split -> 1152 blocks
#define NTILES (NN/QT)        // 144
#define ITERS (NN/MSPLIT/MT)  // 9
#define SLICE (QT*PB)         // 416 floats per partial slice
#define PSCALE 65536.0f
#define PINV   (1.0f/65536.0f)

typedef __bf16 bf16x8 __attribute__((ext_vector_type(8)));
typedef float  f32x4  __attribute__((ext_vector_type(4)));
typedef unsigned short u16;
typedef unsigned int   u32;

static __device__ __forceinline__ u16 f2bf(float x) {
    __hip_bfloat16 h = __float2bfloat16(x);
    return __builtin_bit_cast(u16, h);
}

// Fused producer: blocks [0,144) transpose img1 -> Qt[b][n][c]; blocks
// [144,288) bilinear grid-sample img2 -> Dt[b][m][c]. Block 0 zeroes d_out.
__global__ __launch_bounds__(256)
void k_prep(const float* __restrict__ img1, const float* __restrict__ img2,
            const float* __restrict__ grid, u16* __restrict__ Qt,
            u16* __restrict__ Dt, float* __restrict__ out) {
    int blk = blockIdx.x;
    if (blk == 0 && threadIdx.x == 0) out[0] = 0.0f;
    bool isg = blk >= 144;
    int bb  = isg ? blk - 144 : blk;
    int bm  = (bb >> 3) * 256 + threadIdx.x;       // b*NN + n, 18*256 = 4608
    int cc0 = (bb & 7) * 16;
    int b   = bm / NN;
    int p   = bm - b * NN;
    u16 tmp[16];
    if (!isg) {
        const float* im = img1 + (size_t)b * CC * NN + (size_t)cc0 * NN;
        #pragma unroll
        for (int c = 0; c < 16; ++c) tmp[c] = f2bf(im[(size_t)c * NN + p]);
        uint4* dst = reinterpret_cast<uint4*>(Qt + (size_t)bm * CC + cc0);
        dst[0] = *reinterpret_cast<uint4*>(&tmp[0]);
        dst[1] = *reinterpret_cast<uint4*>(&tmp[8]);
    } else {
        float gx = grid[bm * 2 + 0];
        float gy = grid[bm * 2 + 1];
        float ix = ((gx + 1.0f) * (float)WW - 1.0f) * 0.5f;
        float iy = ((gy + 1.0f) * (float)HH - 1.0f) * 0.5f;
        float x0f = floorf(ix), y0f = floorf(iy);
        float wx1 = ix - x0f, wy1 = iy - y0f;
        float wx0 = 1.0f - wx1, wy0 = 1.0f - wy1;
        int x0 = (int)x0f, y0 = (int)y0f;
        bool xv0 = (x0 >= 0) && (x0 < WW);
        bool xv1 = (x0 + 1 >= 0) && (x0 + 1 < WW);
        bool yv0 = (y0 >= 0) && (y0 < HH);
        bool yv1 = (y0 + 1 >= 0) && (y0 + 1 < HH);
        int x0c = min(max(x0, 0), WW - 1), x1c = min(max(x0 + 1, 0), WW - 1);
        int y0c = min(max(y0, 0), HH - 1), y1c = min(max(y0 + 1, 0), HH - 1);
        float w00 = (xv0 && yv0) ? wx0 * wy0 : 0.0f;
        float w01 = (xv1 && yv0) ? wx1 * wy0 : 0.0f;
        float w10 = (xv0 && yv1) ? wx0 * wy1 : 0.0f;
        float w11 = (xv1 && yv1) ? wx1 * wy1 : 0.0f;
        int p00 = y0c * WW + x0c, p01 = y0c * WW + x1c;
        int p10 = y1c * WW + x0c, p11 = y1c * WW + x1c;
        const float* im = img2 + (size_t)b * CC * NN + (size_t)cc0 * NN;
        #pragma unroll
        for (int c = 0; c < 16; ++c) {
            const float* pl = im + (size_t)c * NN;
            tmp[c] = f2bf(pl[p00] * w00 + pl[p01] * w01 + pl[p10] * w10 + pl[p11] * w11);
        }
        uint4* dst = reinterpret_cast<uint4*>(Dt + (size_t)bm * CC + cc0);
        dst[0] = *reinterpret_cast<uint4*>(&tmp[0]);
        dst[1] = *reinterpret_cast<uint4*>(&tmp[8]);
    }
}

// main: 16x16x32 MFMA, C[m][q], q = lane&15. No LDS tile staging (each D row
// is consumed by exactly one wave): A fragments loaded global->VGPR with
// one-iteration software prefetch; Q fragments (iter-invariant) hoisted to
// VGPRs. Zero barriers in the K-loop. LDS = private per-thread hists (plain
// RMW, no float atomics) + u32 fixed-point positives hist (native atomics).
// Partial hists plain-stored to per-block global slices; NO device-scope
// fences anywhere (R5 lesson: cross-block coherence = L2 writeback storm).
__global__ __launch_bounds__(256)
void k_main(const u16* __restrict__ Qt, const u16* __restrict__ Dt,
            float* __restrict__ Hall, float* __restrict__ Hpos) {
    __shared__ float priv[256 * HST];   // 27648 B per-thread hists
    __shared__ u32   poshu[QT * PB];    //  1664 B positives (u32 fixed-point)

    int tid  = threadIdx.x;
    int bidx = blockIdx.x;              // ((b*144 + ntile)*4 + ms)
    int b     = bidx / (NTILES * MSPLIT);
    int rem   = bidx % (NTILES * MSPLIT);
    int ntile = rem / MSPLIT;
    int ms    = rem % MSPLIT;
    int n0 = ntile * QT;

    for (int i = tid; i < 256 * HST; i += 256) priv[i] = 0.0f;
    for (int i = tid; i < QT * PB; i += 256) poshu[i] = 0u;

    int lane = tid & 63, wave = tid >> 6, quad = lane >> 4, l15 = lane & 15;
    int q  = l15;
    int n  = n0 + q;
    int rn = n / WW, cn = n % WW;
    float* ph = &priv[tid * HST];

    // B fragments (Q rows) — iter-invariant, straight from global (L2-hot)
    const u16* qrow = Qt + ((size_t)(b * NN + n0 + l15)) * CC + quad * 8;
    bf16x8 bv0 = *reinterpret_cast<const bf16x8*>(qrow);
    bf16x8 bv1 = *reinterpret_cast<const bf16x8*>(qrow + 32);
    bf16x8 bv2 = *reinterpret_cast<const bf16x8*>(qrow + 64);
    bf16x8 bv3 = *reinterpret_cast<const bf16x8*>(qrow + 96);

    __syncthreads();                    // hist zero-init visible to all

    int mstart = ms * (NN / MSPLIT);
    const u16* arow = Dt + ((size_t)(b * NN + mstart + wave * 16 + l15)) * CC + quad * 8;
    bf16x8 a0 = *reinterpret_cast<const bf16x8*>(arow);
    bf16x8 a1 = *reinterpret_cast<const bf16x8*>(arow + 32);
    bf16x8 a2 = *reinterpret_cast<const bf16x8*>(arow + 64);
    bf16x8 a3 = *reinterpret_cast<const bf16x8*>(arow + 96);

    for (int it = 0; it < ITERS; ++it) {
        bf16x8 c0v = a0, c1v = a1, c2v = a2, c3v = a3;
        if (it + 1 < ITERS) {           // prefetch next iter's A rows
            const u16* nx = arow + (size_t)(it + 1) * MT * CC;
            a0 = *reinterpret_cast<const bf16x8*>(nx);
            a1 = *reinterpret_cast<const bf16x8*>(nx + 32);
            a2 = *reinterpret_cast<const bf16x8*>(nx + 64);
            a3 = *reinterpret_cast<const bf16x8*>(nx + 96);
        }
        f32x4 acc = {0.f, 0.f, 0.f, 0.f};
        acc = __builtin_amdgcn_mfma_f32_16x16x32_bf16(c0v, bv0, acc, 0, 0, 0);
        acc = __builtin_amdgcn_mfma_f32_16x16x32_bf16(c1v, bv1, acc, 0, 0, 0);
        acc = __builtin_amdgcn_mfma_f32_16x16x32_bf16(c2v, bv2, acc, 0, 0, 0);
        acc = __builtin_amdgcn_mfma_f32_16x16x32_bf16(c3v, bv3, acc, 0, 0, 0);

        int mb = mstart + it * MT + wave * 16 + quad * 4;  // C row = quad*4+i
        #pragma unroll
        for (int i = 0; i < 4; ++i) {
            float s  = acc[i];
            float t  = fminf(fmaxf(fmaf(-12.0f, s, 12.0f), 0.0f), 24.0f);
            float cf = floorf(t);
            float f  = t - cf;
            int   c0b = (int)cf;        // [0,24]; c0==24 -> f==0 -> spill +0
            float h0 = ph[c0b], h1 = ph[c0b + 1];
            ph[c0b]     = h0 + (1.0f - f);   // private -> plain RMW, race-free
            ph[c0b + 1] = h1 + f;
            int m  = mb + i;
            int rm = m / WW, cm = m - rm * WW;
            int dr = rn - rm, dc = cn - cm;
            if ((unsigned)(dr + 4) <= 8u && (unsigned)(dc + 4) <= 8u) {
                u32 w0 = (u32)(fmaf(-PSCALE, f, PSCALE) + 0.5f);
                u32 w1 = (u32)(f * PSCALE + 0.5f);
                atomicAdd(&poshu[q * PB + c0b],     w0);   // native u32 LDS atomic
                atomicAdd(&poshu[q * PB + c0b + 1], w1);
            }
        }
    }
    __syncthreads();
    // flush partial slices, [c][q] layout (coalesced both sides)
    float* oa = Hall + (size_t)bidx * SLICE;
    float* op = Hpos + (size_t)bidx * SLICE;
    for (int idx = tid; idx < SLICE; idx += 256) {
        int c = idx >> 4, qq = idx & 15;
        float s2 = 0.0f;
        #pragma unroll
        for (int j = 0; j < 16; ++j) s2 += priv[(j * 16 + qq) * HST + c];
        oa[idx] = s2;
        op[idx] = (float)poshu[qq * PB + c] * PINV;
    }
}

// AP from MSPLIT partial hists + reliability + mean -> scalar
__global__ __launch_bounds__(256)
void k_finalize(const float* __restrict__ Hall, const float* __restrict__ Hpos,
                const float* __restrict__ rel, float* __restrict__ out) {
    int gid = blockIdx.x * 256 + threadIdx.x;   // 0..4607
    int b = gid / NN, nloc = gid % NN;
    int ntile = nloc >> 4, qq = nloc & 15;
    size_t base = ((size_t)(b * NTILES + ntile) * MSPLIT) * SLICE + qq;
    const float* ha = Hall + base;
    const float* hp = Hpos + base;
    float cumr = 0.f, cumn = 0.f, apn = 0.f, totr = 0.f;
    #pragma unroll
    for (int c = 0; c < 25; ++c) {
        float a = 0.f, r = 0.f;
        #pragma unroll
        for (int s = 0; s < MSPLIT; ++s) {
            a += ha[(size_t)s * SLICE + c * 16];
            r += hp[(size_t)s * SLICE + c * 16];
        }
        cumr += r; cumn += a;
        apn  += (cumr / (1e-16f + cumn)) * r;
        totr += r;
    }
    float ap = apn / totr;                      // totr >= 1 (self-match)
    float rl = rel[gid];
    float loss = 1.0f - (ap * rl + 0.5f * (1.0f - rl));

    for (int off = 32; off > 0; off >>= 1) loss += __shfl_down(loss, off, 64);
    __shared__ float wsum[4];
    int ln = threadIdx.x & 63, wv = threadIdx.x >> 6;
    if (ln == 0) wsum[wv] = loss;
    __syncthreads();
    if (threadIdx.x == 0) {
        float t = wsum[0] + wsum[1] + wsum[2] + wsum[3];
        atomicAdd(out, t * (1.0f / (float)(BB * NN)));
    }
}

extern "C" void kernel_launch(void* const* d_in, const int* in_sizes, int n_in,
                              void* d_out, int out_size, void* d_ws, size_t ws_size,
                              hipStream_t stream) {
    const float* img1 = (const float*)d_in[0];
    const float* img2 = (const float*)d_in[1];
    const float* rel  = (const float*)d_in[2];
    const float* grid = (const float*)d_in[3];

    char* ws = (char*)d_ws;
    const size_t qt_bytes   = (size_t)BB * NN * CC * sizeof(u16);                    // 1.18 MB
    const size_t part_bytes = (size_t)BB * NTILES * MSPLIT * SLICE * sizeof(float);  // 1.92 MB
    u16*   Qt   = (u16*)ws;
    u16*   Dt   = (u16*)(ws + qt_bytes);
    float* Hall = (float*)(ws + 2 * qt_bytes);
    float* Hpos = (float*)(ws + 2 * qt_bytes + part_bytes);

    k_prep    <<<288, 256, 0, stream>>>(img1, img2, grid, Qt, Dt, (float*)d_out);
    k_main    <<<BB * NTILES * MSPLIT, 256, 0, stream>>>(Qt, Dt, Hall, Hpos);
    k_finalize<<<(BB * NN) / 256, 256, 0, stream>>>(Hall, Hpos, rel, (float*)d_out);
}